// Round 1
// baseline (765.669 us; speedup 1.0000x reference)
//
#include <hip/hip_runtime.h>

// Problem constants (z: [16,256,64,64] f32, embedding: [1024,256] f32)
#define BB 16
#define CC 256
#define HH 64
#define WW 64
#define NN 65536   // B*H*W
#define KK 1024
#define MARGIN 1e-3f   // rescue margin: >> bf16x3 distance error (~3e-6)

typedef __bf16 bf16x8 __attribute__((ext_vector_type(8)));
typedef float f32x16 __attribute__((ext_vector_type(16)));

// bf16 round-to-nearest-even split helpers (bit-level, header-version-proof)
__device__ inline unsigned short f2bf(float x){
  unsigned u = __float_as_uint(x);
  u += 0x7FFFu + ((u >> 16) & 1u);
  return (unsigned short)(u >> 16);
}
__device__ inline float bf2f(unsigned short h){
  return __uint_as_float(((unsigned)h) << 16);
}

// ---------------- K0: normalize codebook rows, split to bf16 hi/lo, store ||wn||^2
__global__ __launch_bounds__(64) void kern_prep(const float* __restrict__ emb,
    float* __restrict__ wn, unsigned short* __restrict__ wnh,
    unsigned short* __restrict__ wnl, float* __restrict__ wnn)
{
  const int k = blockIdx.x, t = threadIdx.x;
  float4 v = ((const float4*)emb)[k*64 + t];
  float ss = fmaf(v.x, v.x, fmaf(v.y, v.y, fmaf(v.z, v.z, v.w * v.w)));
  #pragma unroll
  for (int m = 32; m > 0; m >>= 1) ss += __shfl_xor(ss, m, 64);
  float d = fmaxf(sqrtf(ss), 1e-12f);
  float w0 = v.x / d, w1 = v.y / d, w2 = v.z / d, w3 = v.w / d;
  ((float4*)wn)[k*64 + t] = make_float4(w0, w1, w2, w3);
  ushort4 hh, ll;
  hh.x = f2bf(w0); ll.x = f2bf(w0 - bf2f(hh.x));
  hh.y = f2bf(w1); ll.y = f2bf(w1 - bf2f(hh.y));
  hh.z = f2bf(w2); ll.z = f2bf(w2 - bf2f(hh.z));
  hh.w = f2bf(w3); ll.w = f2bf(w3 - bf2f(hh.w));
  ((ushort4*)wnh)[k*64 + t] = hh;
  ((ushort4*)wnl)[k*64 + t] = ll;
  float s2 = fmaf(w0, w0, fmaf(w1, w1, fmaf(w2, w2, w3 * w3)));
  #pragma unroll
  for (int m = 32; m > 0; m >>= 1) s2 += __shfl_xor(s2, m, 64);
  if (t == 0) wnn[k] = s2;
}

// ---------------- K1: L2-normalize z along W, transpose [B,C,H,W]->[N,C], split bf16 hi/lo
// grid: (b*64+h)*4 + c-tile ; block 256
__global__ __launch_bounds__(256) void kern_znorm(const float* __restrict__ z,
    unsigned short* __restrict__ zfh, unsigned short* __restrict__ zfl)
{
  __shared__ float tile[64][65];  // [c_local][w], +1 pad
  __shared__ float sinv[64];
  const int t = threadIdx.x;
  const int ct = blockIdx.x & 3;
  const int bh = blockIdx.x >> 2;     // b*64 + h
  const int c0 = ct * 64;
  const int cl = t >> 2, q = t & 3;
  const float4* zr = (const float4*)(z + ((size_t)(bh >> 6) * 256 + c0 + cl) * 4096
                                       + (size_t)(bh & 63) * 64);
  #pragma unroll
  for (int i = 0; i < 4; i++){
    float4 v = zr[q + 4*i];
    int w = (q + 4*i) * 4;
    tile[cl][w] = v.x; tile[cl][w+1] = v.y; tile[cl][w+2] = v.z; tile[cl][w+3] = v.w;
  }
  __syncthreads();
  if (t < 64){
    float ss = 0.f;
    #pragma unroll
    for (int w = 0; w < 64; w++){ float x = tile[t][w]; ss = fmaf(x, x, ss); }
    sinv[t] = 1.0f / fmaxf(sqrtf(ss), 1e-12f);
  }
  __syncthreads();
  const int cg = (t & 15) * 4, wl = t >> 4;
  #pragma unroll
  for (int rd = 0; rd < 4; rd++){
    int w = wl + 16 * rd;
    size_t n = (size_t)bh * 64 + w;
    ushort4 hh, ll;
    float v0 = tile[cg+0][w] * sinv[cg+0];
    float v1 = tile[cg+1][w] * sinv[cg+1];
    float v2 = tile[cg+2][w] * sinv[cg+2];
    float v3 = tile[cg+3][w] * sinv[cg+3];
    hh.x = f2bf(v0); ll.x = f2bf(v0 - bf2f(hh.x));
    hh.y = f2bf(v1); ll.y = f2bf(v1 - bf2f(hh.y));
    hh.z = f2bf(v2); ll.z = f2bf(v2 - bf2f(hh.z));
    hh.w = f2bf(v3); ll.w = f2bf(v3 - bf2f(hh.w));
    *(ushort4*)(zfh + n*256 + c0 + cg) = hh;
    *(ushort4*)(zfl + n*256 + c0 + cg) = ll;
  }
}

// ---------------- K2: split-bf16 MFMA distance GEMM + running argmin + near-tie flags
// 512 blocks x 256 thr; 4 waves/block, 32 rows/wave. A frags in regs, B tiles in LDS.
__global__ __launch_bounds__(256, 2) void kern_gemm(
    const unsigned short* __restrict__ zfh, const unsigned short* __restrict__ zfl,
    const unsigned short* __restrict__ wnh, const unsigned short* __restrict__ wnl,
    const float* __restrict__ wnn,
    int* __restrict__ idx_i, float* __restrict__ idx_f,
    int* __restrict__ flag_list, unsigned int* __restrict__ flag_count)
{
  __shared__ uint4 sB[2][32 * 33];  // [hi/lo][32 codes x 33 uint4 (pad 16B: 4-way max bank alias)]
  const int t = threadIdx.x;
  const int wv = t >> 6;
  const int lane = t & 63;
  const int col = lane & 31;   // MFMA col (code within tile) == A row lane field
  const int half = lane >> 5;
  const int rowBase = blockIdx.x * 128 + wv * 32;
  const int myRow = rowBase + col;

  // A fragments: zf rows, 16 K-steps of 16 c each; lane holds c = 16s + half*8 + j
  bf16x8 a_hi[16], a_lo[16];
  {
    const uint4* rH = (const uint4*)zfh + (size_t)myRow * 32;
    const uint4* rL = (const uint4*)zfl + (size_t)myRow * 32;
    #pragma unroll
    for (int s = 0; s < 16; s++){
      a_hi[s] = __builtin_bit_cast(bf16x8, rH[2*s + half]);
      a_lo[s] = __builtin_bit_cast(bf16x8, rL[2*s + half]);
    }
  }
  float best[16]; int bidx[16];
  #pragma unroll
  for (int r = 0; r < 16; r++){ best[r] = 3.0e38f; bidx[r] = 0; }
  unsigned int flags = 0;

  for (int kt = 0; kt < 32; kt++){
    const int k0 = kt * 32;
    __syncthreads();
    {
      const uint4* gH = (const uint4*)wnh + (size_t)k0 * 32;
      const uint4* gL = (const uint4*)wnl + (size_t)k0 * 32;
      #pragma unroll
      for (int i = 0; i < 4; i++){
        int g = t + i * 256;
        int r = g >> 5, p = g & 31;
        sB[0][r*33 + p] = gH[g];
        sB[1][r*33 + p] = gL[g];
      }
    }
    __syncthreads();
    f32x16 acc;
    #pragma unroll
    for (int i = 0; i < 16; i++) acc[i] = 0.0f;
    const uint4* bH = &sB[0][col*33 + half];
    const uint4* bL = &sB[1][col*33 + half];
    #pragma unroll
    for (int s = 0; s < 16; s++){
      bf16x8 bh = __builtin_bit_cast(bf16x8, bH[2*s]);
      bf16x8 bl = __builtin_bit_cast(bf16x8, bL[2*s]);
      // fp32-accurate dot via 3 bf16 passes (drop al*bl ~2^-18 rel)
      acc = __builtin_amdgcn_mfma_f32_32x32x16_bf16(a_hi[s], bh, acc, 0, 0, 0);
      acc = __builtin_amdgcn_mfma_f32_32x32x16_bf16(a_lo[s], bh, acc, 0, 0, 0);
      acc = __builtin_amdgcn_mfma_f32_32x32x16_bf16(a_hi[s], bl, acc, 0, 0, 0);
    }
    const float wk = wnn[k0 + col];
    const int kcode = k0 + col;
    #pragma unroll
    for (int r = 0; r < 16; r++){
      float s = fmaf(-2.0f, acc[r], wk);  // d' = ||wn||^2 - 2 dot (row-const dropped)
      if (fabsf(s - best[r]) < MARGIN) flags |= (1u << r);
      if (s < best[r]){ best[r] = s; bidx[r] = kcode; }  // strict < => first-occurrence argmin
    }
  }
  // butterfly min-reduce across the 32 col-lanes (disjoint code subsets)
  #pragma unroll
  for (int m = 1; m < 32; m <<= 1){
    unsigned int oflags = (unsigned int)__shfl_xor((int)flags, m, 64);
    unsigned int nflags = 0;
    #pragma unroll
    for (int r = 0; r < 16; r++){
      float ob = __shfl_xor(best[r], m, 64);
      int oi = __shfl_xor(bidx[r], m, 64);
      bool near = fabsf(best[r] - ob) < MARGIN;
      bool take = (ob < best[r]) || ((ob == best[r]) && (oi < bidx[r]));
      bool wf = take ? ((oflags >> r) & 1u) : ((flags >> r) & 1u);
      if (take){ best[r] = ob; bidx[r] = oi; }
      if (wf || near) nflags |= (1u << r);
    }
    flags = nflags;
  }
  if (col == 0){  // lanes 0 and 32 write the wave's 32 rows
    #pragma unroll
    for (int r = 0; r < 16; r++){
      int rowD = (r & 3) + 8 * (r >> 2) + 4 * half;  // verified C/D mapping [m74/m101]
      int n = rowBase + rowD;
      int bi = bidx[r];
      idx_i[n] = bi;
      idx_f[n] = (float)bi;
      if ((flags >> r) & 1u){
        unsigned int p = atomicAdd(flag_count, 1u);
        flag_list[p] = n;
      }
    }
  }
}

// ---------------- K2b: exact-fp32 rescore of near-tie rows (fp32-faithful argmin)
__global__ __launch_bounds__(256) void kern_rescue(
    const unsigned short* __restrict__ zfh, const unsigned short* __restrict__ zfl,
    const float* __restrict__ wn, const float* __restrict__ wnn,
    const int* __restrict__ flag_list, const unsigned int* __restrict__ flag_count,
    int* __restrict__ idx_i, float* __restrict__ idx_f)
{
  __shared__ float sz[256];
  __shared__ float sv[256];
  __shared__ int si[256];
  const int t = threadIdx.x;
  const int cnt = (int)*flag_count;
  for (int it = blockIdx.x; it < cnt; it += gridDim.x){
    const int n = flag_list[it];
    __syncthreads();
    sz[t] = bf2f(zfh[(size_t)n*256 + t]) + bf2f(zfl[(size_t)n*256 + t]);  // ~2^-18-exact zf
    __syncthreads();
    float bestv = 3.0e38f; int besti = 0;
    #pragma unroll
    for (int j = 0; j < 4; j++){
      const int k = t*4 + j;
      const float* wr = wn + (size_t)k*256;
      float dot = 0.f;
      for (int c = 0; c < 256; c++) dot = fmaf(sz[c], wr[c], dot);
      float s = fmaf(-2.f, dot, wnn[k]);
      if (s < bestv){ bestv = s; besti = k; }
    }
    sv[t] = bestv; si[t] = besti;
    __syncthreads();
    for (int off = 128; off > 0; off >>= 1){
      if (t < off){
        float ov = sv[t+off]; int oi = si[t+off];
        if (ov < sv[t] || (ov == sv[t] && oi < si[t])){ sv[t] = ov; si[t] = oi; }
      }
      __syncthreads();
    }
    if (t == 0){ idx_i[n] = si[0]; idx_f[n] = (float)si[0]; }
  }
}

// ---------------- K3: gather z_q = embedding[idx] back to [B,C,H,W] + commitment-loss sum
__global__ __launch_bounds__(256) void kern_gather(
    const float* __restrict__ z, const float* __restrict__ emb,
    const int* __restrict__ idx_i, float* __restrict__ out,
    float* __restrict__ loss_acc)
{
  __shared__ float tile[64][65];
  __shared__ float zq[64][65];
  __shared__ float sinv[64];
  __shared__ int sidx[64];
  __shared__ float swsum[4];
  const int t = threadIdx.x;
  const int ct = blockIdx.x & 3;
  const int bh = blockIdx.x >> 2;
  const int c0 = ct * 64;
  const int cl = t >> 2, q = t & 3;
  const float4* zr = (const float4*)(z + ((size_t)(bh >> 6) * 256 + c0 + cl) * 4096
                                       + (size_t)(bh & 63) * 64);
  #pragma unroll
  for (int i = 0; i < 4; i++){
    float4 v = zr[q + 4*i];
    int w = (q + 4*i) * 4;
    tile[cl][w] = v.x; tile[cl][w+1] = v.y; tile[cl][w+2] = v.z; tile[cl][w+3] = v.w;
  }
  if (t < 64) sidx[t] = idx_i[bh*64 + t];
  __syncthreads();
  if (t < 64){
    float ss = 0.f;
    #pragma unroll
    for (int w = 0; w < 64; w++){ float x = tile[t][w]; ss = fmaf(x, x, ss); }
    sinv[t] = 1.0f / fmaxf(sqrtf(ss), 1e-12f);
  }
  __syncthreads();
  {
    const int wvv = t >> 6, l = t & 63;
    #pragma unroll
    for (int i = 0; i < 16; i++){
      int w = wvv * 16 + i;
      zq[l][w] = emb[(size_t)sidx[w] * 256 + c0 + l];  // coalesced emb row read
    }
  }
  __syncthreads();
  float lsum = 0.f;
  const int rr = t >> 4, w4 = (t & 15) * 4;
  #pragma unroll
  for (int rd = 0; rd < 4; rd++){
    int r = rr + 16 * rd;
    float inv = sinv[r];
    float q0 = zq[r][w4+0], q1 = zq[r][w4+1], q2 = zq[r][w4+2], q3 = zq[r][w4+3];
    float d0 = q0 - tile[r][w4+0] * inv;
    float d1 = q1 - tile[r][w4+1] * inv;
    float d2 = q2 - tile[r][w4+2] * inv;
    float d3 = q3 - tile[r][w4+3] * inv;
    lsum = fmaf(d0, d0, lsum); lsum = fmaf(d1, d1, lsum);
    lsum = fmaf(d2, d2, lsum); lsum = fmaf(d3, d3, lsum);
    *(float4*)(out + ((size_t)(bh >> 6) * 256 + c0 + r) * 4096
                   + (size_t)(bh & 63) * 64 + w4) = make_float4(q0, q1, q2, q3);
  }
  #pragma unroll
  for (int m = 32; m > 0; m >>= 1) lsum += __shfl_down(lsum, m, 64);
  if ((t & 63) == 0) swsum[t >> 6] = lsum;
  __syncthreads();
  if (t == 0) atomicAdd(loss_acc, swsum[0] + swsum[1] + swsum[2] + swsum[3]);
}

// ---------------- K4: finalize loss = (1 + BETA) * mean
__global__ void kern_final(const float* __restrict__ loss_acc, float* __restrict__ out_loss){
  if (threadIdx.x == 0 && blockIdx.x == 0)
    out_loss[0] = 1.25f * loss_acc[0] * (1.0f / 16777216.0f);
}

extern "C" void kernel_launch(void* const* d_in, const int* in_sizes, int n_in,
                              void* d_out, int out_size, void* d_ws, size_t ws_size,
                              hipStream_t stream)
{
  const float* z   = (const float*)d_in[0];
  const float* emb = (const float*)d_in[1];
  char* ws = (char*)d_ws;
  // workspace layout (66.5 MB total)
  unsigned int* flag_count = (unsigned int*)(ws + 0);
  float* loss_acc          = (float*)(ws + 8);
  float* wnn               = (float*)(ws + 1024);
  float* wn                = (float*)(ws + 8192);
  unsigned short* wnh      = (unsigned short*)(ws + 1056768);
  unsigned short* wnl      = (unsigned short*)(ws + 1581056);
  int* idx_i               = (int*)(ws + 2105344);
  int* flag_list           = (int*)(ws + 2367488);
  unsigned short* zfh      = (unsigned short*)(ws + 2629632);
  unsigned short* zfl      = (unsigned short*)(ws + 36184064);
  float* out_zq   = (float*)d_out;
  float* out_idx  = (float*)d_out + 16777216;
  float* out_loss = (float*)d_out + 16842752;

  hipMemsetAsync(ws, 0, 16, stream);  // flag_count + loss accumulator
  kern_prep<<<KK, 64, 0, stream>>>(emb, wn, wnh, wnl, wnn);
  kern_znorm<<<4096, 256, 0, stream>>>(z, zfh, zfl);
  kern_gemm<<<512, 256, 0, stream>>>(zfh, zfl, wnh, wnl, wnn, idx_i, out_idx,
                                     flag_list, flag_count);
  kern_rescue<<<128, 256, 0, stream>>>(zfh, zfl, wn, wnn, flag_list, flag_count,
                                       idx_i, out_idx);
  kern_gather<<<4096, 256, 0, stream>>>(z, emb, idx_i, out_zq, loss_acc);
  kern_final<<<1, 64, 0, stream>>>(loss_acc, out_loss);
}

// Round 3
// 423.951 us; speedup vs baseline: 1.8060x; 1.8060x over previous
//
#include <hip/hip_runtime.h>

// Problem constants (z: [16,256,64,64] f32, embedding: [1024,256] f32)
#define BB 16
#define CC 256
#define HH 64
#define WW 64
#define NN 65536   // B*H*W
#define KK 1024
#define MARGIN 1e-3f   // final top-2 gap threshold; noise bound ~1e-4 worst-case -> 10x headroom

typedef __bf16 bf16x8 __attribute__((ext_vector_type(8)));
typedef float f32x16 __attribute__((ext_vector_type(16)));

// bf16 round-to-nearest-even split helpers (bit-level, header-version-proof)
__device__ inline unsigned short f2bf(float x){
  unsigned u = __float_as_uint(x);
  u += 0x7FFFu + ((u >> 16) & 1u);
  return (unsigned short)(u >> 16);
}
__device__ inline float bf2f(unsigned short h){
  return __uint_as_float(((unsigned)h) << 16);
}

// ---------------- K0: normalize codebook rows, split to bf16 hi/lo, store ||wn||^2
__global__ __launch_bounds__(64) void kern_prep(const float* __restrict__ emb,
    float* __restrict__ wn, unsigned short* __restrict__ wnh,
    unsigned short* __restrict__ wnl, float* __restrict__ wnn)
{
  const int k = blockIdx.x, t = threadIdx.x;
  float4 v = ((const float4*)emb)[k*64 + t];
  float ss = fmaf(v.x, v.x, fmaf(v.y, v.y, fmaf(v.z, v.z, v.w * v.w)));
  #pragma unroll
  for (int m = 32; m > 0; m >>= 1) ss += __shfl_xor(ss, m, 64);
  float d = fmaxf(sqrtf(ss), 1e-12f);
  float w0 = v.x / d, w1 = v.y / d, w2 = v.z / d, w3 = v.w / d;
  ((float4*)wn)[k*64 + t] = make_float4(w0, w1, w2, w3);
  ushort4 hh, ll;
  hh.x = f2bf(w0); ll.x = f2bf(w0 - bf2f(hh.x));
  hh.y = f2bf(w1); ll.y = f2bf(w1 - bf2f(hh.y));
  hh.z = f2bf(w2); ll.z = f2bf(w2 - bf2f(hh.z));
  hh.w = f2bf(w3); ll.w = f2bf(w3 - bf2f(hh.w));
  ((ushort4*)wnh)[k*64 + t] = hh;
  ((ushort4*)wnl)[k*64 + t] = ll;
  float s2 = fmaf(w0, w0, fmaf(w1, w1, fmaf(w2, w2, w3 * w3)));
  #pragma unroll
  for (int m = 32; m > 0; m >>= 1) s2 += __shfl_xor(s2, m, 64);
  if (t == 0) wnn[k] = s2;
}

// ---------------- K1: L2-normalize z along W, transpose [B,C,H,W]->[N,C], split bf16 hi/lo
__global__ __launch_bounds__(256) void kern_znorm(const float* __restrict__ z,
    unsigned short* __restrict__ zfh, unsigned short* __restrict__ zfl)
{
  __shared__ float tile[64][65];  // [c_local][w], +1 pad
  __shared__ float sinv[64];
  const int t = threadIdx.x;
  const int ct = blockIdx.x & 3;
  const int bh = blockIdx.x >> 2;     // b*64 + h
  const int c0 = ct * 64;
  const int cl = t >> 2, q = t & 3;
  const float4* zr = (const float4*)(z + ((size_t)(bh >> 6) * 256 + c0 + cl) * 4096
                                       + (size_t)(bh & 63) * 64);
  #pragma unroll
  for (int i = 0; i < 4; i++){
    float4 v = zr[q + 4*i];
    int w = (q + 4*i) * 4;
    tile[cl][w] = v.x; tile[cl][w+1] = v.y; tile[cl][w+2] = v.z; tile[cl][w+3] = v.w;
  }
  __syncthreads();
  if (t < 64){
    float ss = 0.f;
    #pragma unroll
    for (int w = 0; w < 64; w++){ float x = tile[t][w]; ss = fmaf(x, x, ss); }
    sinv[t] = 1.0f / fmaxf(sqrtf(ss), 1e-12f);
  }
  __syncthreads();
  const int cg = (t & 15) * 4, wl = t >> 4;
  #pragma unroll
  for (int rd = 0; rd < 4; rd++){
    int w = wl + 16 * rd;
    size_t n = (size_t)bh * 64 + w;
    ushort4 hh, ll;
    float v0 = tile[cg+0][w] * sinv[cg+0];
    float v1 = tile[cg+1][w] * sinv[cg+1];
    float v2 = tile[cg+2][w] * sinv[cg+2];
    float v3 = tile[cg+3][w] * sinv[cg+3];
    hh.x = f2bf(v0); ll.x = f2bf(v0 - bf2f(hh.x));
    hh.y = f2bf(v1); ll.y = f2bf(v1 - bf2f(hh.y));
    hh.z = f2bf(v2); ll.z = f2bf(v2 - bf2f(hh.z));
    hh.w = f2bf(v3); ll.w = f2bf(v3 - bf2f(hh.w));
    *(ushort4*)(zfh + n*256 + c0 + cg) = hh;
    *(ushort4*)(zfl + n*256 + c0 + cg) = ll;
  }
}

// ---------------- K2: split-bf16 MFMA distance GEMM + argmin + exact final top-2 gap flags
__global__ __launch_bounds__(256, 2) void kern_gemm(
    const unsigned short* __restrict__ zfh, const unsigned short* __restrict__ zfl,
    const unsigned short* __restrict__ wnh, const unsigned short* __restrict__ wnl,
    const float* __restrict__ wnn,
    int* __restrict__ idx_i, float* __restrict__ idx_f,
    int* __restrict__ flag_list, unsigned int* __restrict__ flag_count)
{
  __shared__ uint4 sB[2][32 * 33];
  const int t = threadIdx.x;
  const int wv = t >> 6;
  const int lane = t & 63;
  const int col = lane & 31;
  const int half = lane >> 5;
  const int rowBase = blockIdx.x * 128 + wv * 32;
  const int myRow = rowBase + col;

  bf16x8 a_hi[16], a_lo[16];
  {
    const uint4* rH = (const uint4*)zfh + (size_t)myRow * 32;
    const uint4* rL = (const uint4*)zfl + (size_t)myRow * 32;
    #pragma unroll
    for (int s = 0; s < 16; s++){
      a_hi[s] = __builtin_bit_cast(bf16x8, rH[2*s + half]);
      a_lo[s] = __builtin_bit_cast(bf16x8, rL[2*s + half]);
    }
  }
  float best[16], best2[16]; int bidx[16];
  #pragma unroll
  for (int r = 0; r < 16; r++){ best[r] = 3.0e38f; best2[r] = 3.0e38f; bidx[r] = 0; }

  for (int kt = 0; kt < 32; kt++){
    const int k0 = kt * 32;
    __syncthreads();
    {
      const uint4* gH = (const uint4*)wnh + (size_t)k0 * 32;
      const uint4* gL = (const uint4*)wnl + (size_t)k0 * 32;
      #pragma unroll
      for (int i = 0; i < 4; i++){
        int g = t + i * 256;
        int r = g >> 5, p = g & 31;
        sB[0][r*33 + p] = gH[g];
        sB[1][r*33 + p] = gL[g];
      }
    }
    __syncthreads();
    f32x16 acc;
    #pragma unroll
    for (int i = 0; i < 16; i++) acc[i] = 0.0f;
    const uint4* bH = &sB[0][col*33 + half];
    const uint4* bL = &sB[1][col*33 + half];
    #pragma unroll
    for (int s = 0; s < 16; s++){
      bf16x8 bh = __builtin_bit_cast(bf16x8, bH[2*s]);
      bf16x8 bl = __builtin_bit_cast(bf16x8, bL[2*s]);
      acc = __builtin_amdgcn_mfma_f32_32x32x16_bf16(a_hi[s], bh, acc, 0, 0, 0);
      acc = __builtin_amdgcn_mfma_f32_32x32x16_bf16(a_lo[s], bh, acc, 0, 0, 0);
      acc = __builtin_amdgcn_mfma_f32_32x32x16_bf16(a_hi[s], bl, acc, 0, 0, 0);
    }
    const float wk = wnn[k0 + col];
    const int kcode = k0 + col;
    #pragma unroll
    for (int r = 0; r < 16; r++){
      float s = fmaf(-2.0f, acc[r], wk);  // d' = ||wn||^2 - 2 dot
      if (s < best[r]){ best2[r] = best[r]; best[r] = s; bidx[r] = kcode; }
      else if (s < best2[r]){ best2[r] = s; }
    }
  }
  // butterfly top-2 min-reduce across the 32 col-lanes
  #pragma unroll
  for (int m = 1; m < 32; m <<= 1){
    #pragma unroll
    for (int r = 0; r < 16; r++){
      float ob  = __shfl_xor(best[r],  m, 64);
      float ob2 = __shfl_xor(best2[r], m, 64);
      int   oi  = __shfl_xor(bidx[r],  m, 64);
      bool take = (ob < best[r]) || ((ob == best[r]) && (oi < bidx[r]));
      if (take){
        best2[r] = fminf(ob2, best[r]);   // winner's b2 vs loser's b1
        best[r] = ob; bidx[r] = oi;
      } else {
        best2[r] = fminf(best2[r], ob);
      }
    }
  }
  if (col == 0){  // lanes 0 and 32 write the wave's 32 rows
    #pragma unroll
    for (int r = 0; r < 16; r++){
      int rowD = (r & 3) + 8 * (r >> 2) + 4 * half;  // verified C/D mapping [m74/m101]
      int n = rowBase + rowD;
      int bi = bidx[r];
      idx_i[n] = bi;
      idx_f[n] = (float)bi;
      if (best2[r] - best[r] < MARGIN){
        unsigned int p = atomicAdd(flag_count, 1u);
        flag_list[p] = n;
      }
    }
  }
}

// ---------------- K2b: rescore flagged rows. Per-(row,k) chain is BIT-IDENTICAL to the
// Round-1 passing kernel: serial fp32 fmaf over c=0..255, s=fmaf(-2,dot,wnn[k]),
// global argmin with lowest-index tie-break. Restructured only for throughput:
// 8 rows/block share wn loads (thread: 4 ks x 8 rows = 32 interleaved chains).
__global__ __launch_bounds__(256) void kern_rescue(
    const unsigned short* __restrict__ zfh, const unsigned short* __restrict__ zfl,
    const float* __restrict__ wn, const float* __restrict__ wnn,
    const int* __restrict__ flag_list, const unsigned int* __restrict__ flag_count,
    int* __restrict__ idx_i, float* __restrict__ idx_f)
{
  __shared__ float sz[8][256];
  __shared__ float svw[4];
  __shared__ int   siw[4];
  __shared__ int   srow[8];
  const int t = threadIdx.x;
  const int lane = t & 63, wvi = t >> 6;
  const int cnt = (int)*flag_count;
  const int k0 = t * 4;

  for (int base = blockIdx.x * 8; base < cnt; base += gridDim.x * 8){
    const int nr = min(8, cnt - base);
    __syncthreads();
    for (int i = t; i < nr * 256; i += 256){
      int r = i >> 8, c = i & 255;
      int n = flag_list[base + r];
      sz[r][c] = bf2f(zfh[(size_t)n*256 + c]) + bf2f(zfl[(size_t)n*256 + c]);
    }
    if (t < nr) srow[t] = flag_list[base + t];
    __syncthreads();

    float acc[32];  // [j*8+r]
    #pragma unroll
    for (int i = 0; i < 32; i++) acc[i] = 0.0f;
    const float4* w0 = (const float4*)(wn + (size_t)(k0+0)*256);
    const float4* w1 = (const float4*)(wn + (size_t)(k0+1)*256);
    const float4* w2 = (const float4*)(wn + (size_t)(k0+2)*256);
    const float4* w3 = (const float4*)(wn + (size_t)(k0+3)*256);
    for (int c4 = 0; c4 < 64; c4++){
      float4 wa = w0[c4], wb = w1[c4], wc = w2[c4], wd = w3[c4];
      #pragma unroll
      for (int r = 0; r < 8; r++){
        float4 s = ((const float4*)sz[r])[c4];   // broadcast LDS read
        // in-order c accumulation (x,y,z,w) => same rounding as scalar chain
        acc[0*8+r] = fmaf(s.x, wa.x, acc[0*8+r]);
        acc[0*8+r] = fmaf(s.y, wa.y, acc[0*8+r]);
        acc[0*8+r] = fmaf(s.z, wa.z, acc[0*8+r]);
        acc[0*8+r] = fmaf(s.w, wa.w, acc[0*8+r]);
        acc[1*8+r] = fmaf(s.x, wb.x, acc[1*8+r]);
        acc[1*8+r] = fmaf(s.y, wb.y, acc[1*8+r]);
        acc[1*8+r] = fmaf(s.z, wb.z, acc[1*8+r]);
        acc[1*8+r] = fmaf(s.w, wb.w, acc[1*8+r]);
        acc[2*8+r] = fmaf(s.x, wc.x, acc[2*8+r]);
        acc[2*8+r] = fmaf(s.y, wc.y, acc[2*8+r]);
        acc[2*8+r] = fmaf(s.z, wc.z, acc[2*8+r]);
        acc[2*8+r] = fmaf(s.w, wc.w, acc[2*8+r]);
        acc[3*8+r] = fmaf(s.x, wd.x, acc[3*8+r]);
        acc[3*8+r] = fmaf(s.y, wd.y, acc[3*8+r]);
        acc[3*8+r] = fmaf(s.z, wd.z, acc[3*8+r]);
        acc[3*8+r] = fmaf(s.w, wd.w, acc[3*8+r]);
      }
    }
    for (int r = 0; r < nr; r++){
      float bv = 3.0e38f; int bi = 0;
      #pragma unroll
      for (int j = 0; j < 4; j++){
        float s = fmaf(-2.0f, acc[j*8+r], wnn[k0+j]);
        if (s < bv){ bv = s; bi = k0 + j; }
      }
      #pragma unroll
      for (int m = 1; m < 64; m <<= 1){
        float ov = __shfl_xor(bv, m, 64);
        int   oi = __shfl_xor(bi, m, 64);
        if (ov < bv || (ov == bv && oi < bi)){ bv = ov; bi = oi; }
      }
      if (lane == 0){ svw[wvi] = bv; siw[wvi] = bi; }
      __syncthreads();
      if (t == 0){
        float fb = svw[0]; int fi = siw[0];
        #pragma unroll
        for (int wq = 1; wq < 4; wq++){
          float ov = svw[wq]; int oi = siw[wq];
          if (ov < fb || (ov == fb && oi < fi)){ fb = ov; fi = oi; }
        }
        idx_i[srow[r]] = fi;
        idx_f[srow[r]] = (float)fi;
      }
      __syncthreads();
    }
  }
}

// ---------------- K3: gather z_q = embedding[idx] back to [B,C,H,W] + commitment-loss sum
__global__ __launch_bounds__(256) void kern_gather(
    const float* __restrict__ z, const float* __restrict__ emb,
    const int* __restrict__ idx_i, float* __restrict__ out,
    float* __restrict__ loss_acc)
{
  __shared__ float tile[64][65];
  __shared__ float zq[64][65];
  __shared__ float sinv[64];
  __shared__ int sidx[64];
  __shared__ float swsum[4];
  const int t = threadIdx.x;
  const int ct = blockIdx.x & 3;
  const int bh = blockIdx.x >> 2;
  const int c0 = ct * 64;
  const int cl = t >> 2, q = t & 3;
  const float4* zr = (const float4*)(z + ((size_t)(bh >> 6) * 256 + c0 + cl) * 4096
                                       + (size_t)(bh & 63) * 64);
  #pragma unroll
  for (int i = 0; i < 4; i++){
    float4 v = zr[q + 4*i];
    int w = (q + 4*i) * 4;
    tile[cl][w] = v.x; tile[cl][w+1] = v.y; tile[cl][w+2] = v.z; tile[cl][w+3] = v.w;
  }
  if (t < 64) sidx[t] = idx_i[bh*64 + t];
  __syncthreads();
  if (t < 64){
    float ss = 0.f;
    #pragma unroll
    for (int w = 0; w < 64; w++){ float x = tile[t][w]; ss = fmaf(x, x, ss); }
    sinv[t] = 1.0f / fmaxf(sqrtf(ss), 1e-12f);
  }
  __syncthreads();
  {
    const int wvv = t >> 6, l = t & 63;
    #pragma unroll
    for (int i = 0; i < 16; i++){
      int w = wvv * 16 + i;
      zq[l][w] = emb[(size_t)sidx[w] * 256 + c0 + l];
    }
  }
  __syncthreads();
  float lsum = 0.f;
  const int rr = t >> 4, w4 = (t & 15) * 4;
  #pragma unroll
  for (int rd = 0; rd < 4; rd++){
    int r = rr + 16 * rd;
    float inv = sinv[r];
    float q0 = zq[r][w4+0], q1 = zq[r][w4+1], q2 = zq[r][w4+2], q3 = zq[r][w4+3];
    float d0 = q0 - tile[r][w4+0] * inv;
    float d1 = q1 - tile[r][w4+1] * inv;
    float d2 = q2 - tile[r][w4+2] * inv;
    float d3 = q3 - tile[r][w4+3] * inv;
    lsum = fmaf(d0, d0, lsum); lsum = fmaf(d1, d1, lsum);
    lsum = fmaf(d2, d2, lsum); lsum = fmaf(d3, d3, lsum);
    *(float4*)(out + ((size_t)(bh >> 6) * 256 + c0 + r) * 4096
                   + (size_t)(bh & 63) * 64 + w4) = make_float4(q0, q1, q2, q3);
  }
  #pragma unroll
  for (int m = 32; m > 0; m >>= 1) lsum += __shfl_down(lsum, m, 64);
  if ((t & 63) == 0) swsum[t >> 6] = lsum;
  __syncthreads();
  if (t == 0) atomicAdd(loss_acc, swsum[0] + swsum[1] + swsum[2] + swsum[3]);
}

// ---------------- K4: finalize loss = (1 + BETA) * mean
__global__ void kern_final(const float* __restrict__ loss_acc, float* __restrict__ out_loss){
  if (threadIdx.x == 0 && blockIdx.x == 0)
    out_loss[0] = 1.25f * loss_acc[0] * (1.0f / 16777216.0f);
}

extern "C" void kernel_launch(void* const* d_in, const int* in_sizes, int n_in,
                              void* d_out, int out_size, void* d_ws, size_t ws_size,
                              hipStream_t stream)
{
  const float* z   = (const float*)d_in[0];
  const float* emb = (const float*)d_in[1];
  char* ws = (char*)d_ws;
  unsigned int* flag_count = (unsigned int*)(ws + 0);
  float* loss_acc          = (float*)(ws + 8);
  float* wnn               = (float*)(ws + 1024);
  float* wn                = (float*)(ws + 8192);
  unsigned short* wnh      = (unsigned short*)(ws + 1056768);
  unsigned short* wnl      = (unsigned short*)(ws + 1581056);
  int* idx_i               = (int*)(ws + 2105344);
  int* flag_list           = (int*)(ws + 2367488);
  unsigned short* zfh      = (unsigned short*)(ws + 2629632);
  unsigned short* zfl      = (unsigned short*)(ws + 36184064);
  float* out_zq   = (float*)d_out;
  float* out_idx  = (float*)d_out + 16777216;
  float* out_loss = (float*)d_out + 16842752;

  hipMemsetAsync(ws, 0, 16, stream);  // flag_count + loss accumulator
  kern_prep<<<KK, 64, 0, stream>>>(emb, wn, wnh, wnl, wnn);
  kern_znorm<<<4096, 256, 0, stream>>>(z, zfh, zfl);
  kern_gemm<<<512, 256, 0, stream>>>(zfh, zfl, wnh, wnl, wnn, idx_i, out_idx,
                                     flag_list, flag_count);
  kern_rescue<<<512, 256, 0, stream>>>(zfh, zfl, wn, wnn, flag_list, flag_count,
                                       idx_i, out_idx);
  kern_gather<<<4096, 256, 0, stream>>>(z, emb, idx_i, out_zq, loss_acc);
  kern_final<<<1, 64, 0, stream>>>(loss_acc, out_loss);
}

// Round 4
// 376.173 us; speedup vs baseline: 2.0354x; 1.1270x over previous
//
#include <hip/hip_runtime.h>

// Problem constants (z: [16,256,64,64] f32, embedding: [1024,256] f32)
#define NN 65536   // B*H*W rows
#define KK 1024
#define TFLAG 6e-3f  // flag if top-2 gap < TFLAG (noise sigma ~3e-4 + key trunc 1e-3 -> ~12 sigma)

typedef __bf16 bf16x8 __attribute__((ext_vector_type(8)));
typedef float f32x16 __attribute__((ext_vector_type(16)));

__device__ __forceinline__ unsigned short f2bf(float x){
  unsigned u = __float_as_uint(x);
  u += 0x7FFFu + ((u >> 16) & 1u);
  return (unsigned short)(u >> 16);
}
__device__ __forceinline__ float bf2f(unsigned short h){
  return __uint_as_float(((unsigned)h) << 16);
}
__device__ __forceinline__ void dma16(const uint4* g, uint4* l){
  __builtin_amdgcn_global_load_lds(
      (const __attribute__((address_space(1))) void*)g,
      (__attribute__((address_space(3))) void*)l, 16, 0, 0);
}
union U4S8 { uint4 v; unsigned short u[8]; };

// Fragment-major layout for bf16 matrices [rows][256 c]:
// uint4 (8 c-elems) for (row n, chunk q=c>>3) at index (n>>5)*1024 + q*32 + (n&31).

// ---------------- K0: normalize codebook, write wn(f32), wnh frag-major, wnn, wnn4
__global__ __launch_bounds__(64) void kern_prep(const float* __restrict__ emb,
    float* __restrict__ wn, uint4* __restrict__ wnh4,
    float* __restrict__ wnn, float* __restrict__ wnn4)
{
  const int k = blockIdx.x, t = threadIdx.x;
  float4 v = ((const float4*)emb)[k*64 + t];
  float ss = fmaf(v.x, v.x, fmaf(v.y, v.y, fmaf(v.z, v.z, v.w * v.w)));
  #pragma unroll
  for (int m = 32; m > 0; m >>= 1) ss += __shfl_xor(ss, m, 64);
  float d = fmaxf(sqrtf(ss), 1e-12f);
  float w0 = v.x / d, w1 = v.y / d, w2 = v.z / d, w3 = v.w / d;
  ((float4*)wn)[k*64 + t] = make_float4(w0, w1, w2, w3);
  // frag-major hi write: c = 4t..4t+3 -> chunk q = t>>1, half-uint4 offset (t&1)*4 shorts
  unsigned short* base = (unsigned short*)wnh4;
  size_t o = ((size_t)(k >> 5) * 1024 + (size_t)(t >> 1) * 32 + (k & 31)) * 8 + (t & 1) * 4;
  base[o+0] = f2bf(w0); base[o+1] = f2bf(w1); base[o+2] = f2bf(w2); base[o+3] = f2bf(w3);
  float s2 = fmaf(w0, w0, fmaf(w1, w1, fmaf(w2, w2, w3 * w3)));
  #pragma unroll
  for (int m = 32; m > 0; m >>= 1) s2 += __shfl_xor(s2, m, 64);
  if (t == 0){ wnn[k] = s2; wnn4[k] = 4.0f - s2; }
}

// ---------------- K1: L2-normalize z along W, transpose to [N,C], split bf16 hi/lo,
// store BOTH in fragment-major layout. grid: (b*64+h)*4 + c-tile; block 256.
__global__ __launch_bounds__(256) void kern_znorm(const float* __restrict__ z,
    uint4* __restrict__ zfh4, uint4* __restrict__ zfl4)
{
  __shared__ float tile[64][65];  // [c_local][w]
  __shared__ float sinv[64];
  const int t = threadIdx.x;
  const int ct = blockIdx.x & 3;
  const int bh = blockIdx.x >> 2;     // b*64 + h
  const int c0 = ct * 64, q0 = ct * 8;
  const int cl = t >> 2, q = t & 3;
  const float4* zr = (const float4*)(z + ((size_t)(bh >> 6) * 256 + c0 + cl) * 4096
                                       + (size_t)(bh & 63) * 64);
  #pragma unroll
  for (int i = 0; i < 4; i++){
    float4 v = zr[q + 4*i];
    int w = (q + 4*i) * 4;
    tile[cl][w] = v.x; tile[cl][w+1] = v.y; tile[cl][w+2] = v.z; tile[cl][w+3] = v.w;
  }
  __syncthreads();
  if (t < 64){
    float ss = 0.f;
    #pragma unroll
    for (int w = 0; w < 64; w++){ float x = tile[t][w]; ss = fmaf(x, x, ss); }
    sinv[t] = 1.0f / fmaxf(sqrtf(ss), 1e-12f);
  }
  __syncthreads();
  // 512 uint4s per block: 2 n-tiles x 8 chunks x 32 cols; 2 per thread
  #pragma unroll
  for (int j = 0; j < 2; j++){
    int p = t + 256 * j;
    int tI = p >> 8, rem = p & 255;
    int qq = rem >> 5, colI = rem & 31;
    int w = tI * 32 + colI;
    U4S8 hh, ll;
    #pragma unroll
    for (int e = 0; e < 8; e++){
      int c = qq * 8 + e;
      float v = tile[c][w] * sinv[c];
      hh.u[e] = f2bf(v);
      ll.u[e] = f2bf(v - bf2f(hh.u[e]));
    }
    size_t o = (size_t)(bh * 2 + tI) * 1024 + (size_t)(q0 + qq) * 32 + colI;
    zfh4[o] = hh.v;
    zfl4[o] = ll.v;
  }
}

// ---------------- K2: 1-pass bf16 MFMA GEMM, 64 rows x 32 codes per wave,
// code-split-2, DMA-staged double-buffered B, packed-key top-2 per row.
// grid 512: block bid -> rows (bid>>1)*256..+255, codes (bid&1)*512..+511.
__global__ __launch_bounds__(256, 2) void kern_gemm(
    const uint4* __restrict__ zA, const uint4* __restrict__ wB,
    const float* __restrict__ wnn4, uint2* __restrict__ pairs)
{
  __shared__ uint4 sB[2][1024];   // [buf][q(0..31) x col(0..31)] for a 32-code tile
  const int t = threadIdx.x;
  const int wv = t >> 6;
  const int lane = t & 63;
  const int col = lane & 31;
  const int half = lane >> 5;
  const int hb = blockIdx.x & 1;
  const int cb = hb * 512;
  const int rowBase = (blockIdx.x >> 1) * 256 + wv * 64;
  const int T0 = rowBase >> 5;    // two A tiles: T0, T0+1

  // resident A fragments: lane holds c = 16s + 8*half + j for rows (tile, col)
  bf16x8 a0[16], a1[16];
  {
    const uint4* r0 = zA + (size_t)T0 * 1024;
    const uint4* r1 = zA + (size_t)(T0 + 1) * 1024;
    // kick off DMA of B tile 0 first so it overlaps the A loads
    const uint4* g0 = wB + (size_t)(cb >> 5) * 1024;
    dma16(g0 + (wv*4+0)*64 + lane, &sB[0][(wv*4+0)*64 + lane]);
    dma16(g0 + (wv*4+1)*64 + lane, &sB[0][(wv*4+1)*64 + lane]);
    dma16(g0 + (wv*4+2)*64 + lane, &sB[0][(wv*4+2)*64 + lane]);
    dma16(g0 + (wv*4+3)*64 + lane, &sB[0][(wv*4+3)*64 + lane]);
    #pragma unroll
    for (int s = 0; s < 16; s++){
      a0[s] = __builtin_bit_cast(bf16x8, r0[(2*s + half)*32 + col]);
      a1[s] = __builtin_bit_cast(bf16x8, r1[(2*s + half)*32 + col]);
    }
  }
  unsigned b1k[2][16], b2k[2][16];
  #pragma unroll
  for (int r = 0; r < 16; r++){
    b1k[0][r] = 0u; b1k[1][r] = 0u; b2k[0][r] = 0u; b2k[1][r] = 0u;
  }
  const int kinvBase = 1023 - cb - col;
  __syncthreads();   // drains DMA tile0 + A loads

  for (int kt = 0; kt < 16; kt++){
    if (kt < 15){
      const uint4* gn = wB + (size_t)((cb >> 5) + kt + 1) * 1024;
      uint4* ld = &sB[(kt + 1) & 1][0];
      dma16(gn + (wv*4+0)*64 + lane, ld + (wv*4+0)*64 + lane);
      dma16(gn + (wv*4+1)*64 + lane, ld + (wv*4+1)*64 + lane);
      dma16(gn + (wv*4+2)*64 + lane, ld + (wv*4+2)*64 + lane);
      dma16(gn + (wv*4+3)*64 + lane, ld + (wv*4+3)*64 + lane);
    }
    const float c4k = wnn4[cb + kt*32 + col];
    const uint4* bp = &sB[kt & 1][half * 32 + col];
    f32x16 acc0, acc1;
    #pragma unroll
    for (int i = 0; i < 16; i++){ acc0[i] = 0.0f; acc1[i] = 0.0f; }
    #pragma unroll
    for (int s = 0; s < 16; s++){
      bf16x8 bs = __builtin_bit_cast(bf16x8, bp[s * 64]);  // (2s+half)*32
      acc0 = __builtin_amdgcn_mfma_f32_32x32x16_bf16(a0[s], bs, acc0, 0, 0, 0);
      acc1 = __builtin_amdgcn_mfma_f32_32x32x16_bf16(a1[s], bs, acc1, 0, 0, 0);
    }
    const unsigned kinv = (unsigned)(kinvBase - kt * 32);
    #pragma unroll
    for (int r = 0; r < 16; r++){
      // s'' = 4 - ||w||^2 + 2*dot  (in (0,5]; argmax s'' == argmin distance)
      float s0 = fmaf(2.0f, acc0[r], c4k);
      unsigned u0 = (__float_as_uint(s0) & 0xFFFFFC00u) | kinv;
      b2k[0][r] = max(b2k[0][r], min(b1k[0][r], u0));
      b1k[0][r] = max(b1k[0][r], u0);
      float s1 = fmaf(2.0f, acc1[r], c4k);
      unsigned u1 = (__float_as_uint(s1) & 0xFFFFFC00u) | kinv;
      b2k[1][r] = max(b2k[1][r], min(b1k[1][r], u1));
      b1k[1][r] = max(b1k[1][r], u1);
    }
    __syncthreads();   // tile kt reads done; tile kt+1 landed
  }
  // butterfly top-2 max-reduce across the 32 col-lanes
  #pragma unroll
  for (int m = 1; m < 32; m <<= 1){
    #pragma unroll
    for (int ti = 0; ti < 2; ti++){
      #pragma unroll
      for (int r = 0; r < 16; r++){
        unsigned o1 = (unsigned)__shfl_xor((int)b1k[ti][r], m, 64);
        unsigned o2 = (unsigned)__shfl_xor((int)b2k[ti][r], m, 64);
        b2k[ti][r] = max(max(b2k[ti][r], o2), min(b1k[ti][r], o1));
        b1k[ti][r] = max(b1k[ti][r], o1);
      }
    }
  }
  if (col == 0){  // lanes 0 and 32 write the wave's 64 rows
    #pragma unroll
    for (int ti = 0; ti < 2; ti++){
      #pragma unroll
      for (int r = 0; r < 16; r++){
        int rowD = (r & 3) + 8 * (r >> 2) + 4 * half;  // verified C/D map [m74/m101]
        int n = rowBase + ti * 32 + rowD;
        pairs[(size_t)n * 2 + hb] = make_uint2(b1k[ti][r], b2k[ti][r]);
      }
    }
  }
}

// ---------------- K2m: merge two code-half top-2s, emit idx + flags
__global__ __launch_bounds__(256) void kern_merge(
    const uint2* __restrict__ pairs, int* __restrict__ idx_i, float* __restrict__ idx_f,
    int* __restrict__ flag_list, unsigned int* __restrict__ flag_count)
{
  const int n = blockIdx.x * 256 + threadIdx.x;
  uint2 p0 = pairs[(size_t)n * 2];
  uint2 p1 = pairs[(size_t)n * 2 + 1];
  unsigned B1 = max(p0.x, p1.x);
  unsigned B2 = max(max(p0.y, p1.y), min(p0.x, p1.x));
  int idx = 1023 - (int)(B1 & 1023u);
  idx_i[n] = idx;
  idx_f[n] = (float)idx;
  float gap = __uint_as_float(B1 & 0xFFFFFC00u) - __uint_as_float(B2 & 0xFFFFFC00u);
  bool f = gap < TFLAG;
  unsigned long long m = __ballot(f);
  if (m){
    int lane = threadIdx.x & 63;
    int leader = __ffsll((unsigned long long)m) - 1;
    unsigned base = 0;
    if (lane == leader) base = atomicAdd(flag_count, (unsigned)__popcll(m));
    base = (unsigned)__shfl((int)base, leader, 64);
    if (f){
      int off = __popcll(m & ((1ull << lane) - 1ull));
      flag_list[base + off] = n;
    }
  }
}

// ---------------- K2b: exact-fp32 rescore of flagged rows.
// Per-(row,k) chain BIT-IDENTICAL to the R1/R3-passed rescue: serial fp32 fmaf
// over c=0..255 (zf reconstructed as hi+lo), s = fmaf(-2, dot, wnn[k]),
// global argmin with lowest-index tie-break. 16 rows/batch.
__global__ __launch_bounds__(256) void kern_rescue(
    const uint4* __restrict__ zfh4, const uint4* __restrict__ zfl4,
    const float* __restrict__ wn, const float* __restrict__ wnn,
    const int* __restrict__ flag_list, const unsigned int* __restrict__ flag_count,
    int* __restrict__ idx_i, float* __restrict__ idx_f)
{
  __shared__ float sz[16][256];
  __shared__ float svw[4];
  __shared__ int   siw[4];
  __shared__ int   srow[16];
  const int t = threadIdx.x;
  const int lane = t & 63, wvi = t >> 6;
  const int cnt = (int)*flag_count;
  const int k0 = t * 4;

  for (int base = blockIdx.x * 16; base < cnt; base += gridDim.x * 16){
    const int nr = min(16, cnt - base);
    __syncthreads();
    if (t < nr) srow[t] = flag_list[base + t];
    __syncthreads();
    for (int p = t; p < nr * 32; p += 256){
      int r = p >> 5, q = p & 31;
      int n = srow[r];
      size_t o = (size_t)(n >> 5) * 1024 + (size_t)q * 32 + (n & 31);
      U4S8 h, l; h.v = zfh4[o]; l.v = zfl4[o];
      #pragma unroll
      for (int e = 0; e < 8; e++) sz[r][q*8 + e] = bf2f(h.u[e]) + bf2f(l.u[e]);
    }
    __syncthreads();

    float acc[64];  // [j*16 + r]
    #pragma unroll
    for (int i = 0; i < 64; i++) acc[i] = 0.0f;
    const float4* w0 = (const float4*)(wn + (size_t)(k0+0)*256);
    const float4* w1 = (const float4*)(wn + (size_t)(k0+1)*256);
    const float4* w2 = (const float4*)(wn + (size_t)(k0+2)*256);
    const float4* w3 = (const float4*)(wn + (size_t)(k0+3)*256);
    for (int c4 = 0; c4 < 64; c4++){
      float4 wa = w0[c4], wb = w1[c4], wc = w2[c4], wd = w3[c4];
      #pragma unroll
      for (int r = 0; r < 16; r++){
        float4 s = ((const float4*)sz[r])[c4];   // broadcast LDS read
        acc[0*16+r] = fmaf(s.x, wa.x, acc[0*16+r]);
        acc[0*16+r] = fmaf(s.y, wa.y, acc[0*16+r]);
        acc[0*16+r] = fmaf(s.z, wa.z, acc[0*16+r]);
        acc[0*16+r] = fmaf(s.w, wa.w, acc[0*16+r]);
        acc[1*16+r] = fmaf(s.x, wb.x, acc[1*16+r]);
        acc[1*16+r] = fmaf(s.y, wb.y, acc[1*16+r]);
        acc[1*16+r] = fmaf(s.z, wb.z, acc[1*16+r]);
        acc[1*16+r] = fmaf(s.w, wb.w, acc[1*16+r]);
        acc[2*16+r] = fmaf(s.x, wc.x, acc[2*16+r]);
        acc[2*16+r] = fmaf(s.y, wc.y, acc[2*16+r]);
        acc[2*16+r] = fmaf(s.z, wc.z, acc[2*16+r]);
        acc[2*16+r] = fmaf(s.w, wc.w, acc[2*16+r]);
        acc[3*16+r] = fmaf(s.x, wd.x, acc[3*16+r]);
        acc[3*16+r] = fmaf(s.y, wd.y, acc[3*16+r]);
        acc[3*16+r] = fmaf(s.z, wd.z, acc[3*16+r]);
        acc[3*16+r] = fmaf(s.w, wd.w, acc[3*16+r]);
      }
    }
    for (int r = 0; r < nr; r++){
      float bv = 3.0e38f; int bi = 0;
      #pragma unroll
      for (int j = 0; j < 4; j++){
        float s = fmaf(-2.0f, acc[j*16 + r], wnn[k0 + j]);
        if (s < bv){ bv = s; bi = k0 + j; }
      }
      #pragma unroll
      for (int m = 1; m < 64; m <<= 1){
        float ov = __shfl_xor(bv, m, 64);
        int   oi = __shfl_xor(bi, m, 64);
        if (ov < bv || (ov == bv && oi < bi)){ bv = ov; bi = oi; }
      }
      if (lane == 0){ svw[wvi] = bv; siw[wvi] = bi; }
      __syncthreads();
      if (t == 0){
        float fb = svw[0]; int fi = siw[0];
        #pragma unroll
        for (int wq = 1; wq < 4; wq++){
          float ov = svw[wq]; int oi = siw[wq];
          if (ov < fb || (ov == fb && oi < fi)){ fb = ov; fi = oi; }
        }
        idx_i[srow[r]] = fi;
        idx_f[srow[r]] = (float)fi;
      }
      __syncthreads();
    }
  }
}

// ---------------- K3: gather z_q = embedding[idx] back to [B,C,H,W] + loss sum
__global__ __launch_bounds__(256) void kern_gather(
    const float* __restrict__ z, const float* __restrict__ emb,
    const int* __restrict__ idx_i, float* __restrict__ out,
    float* __restrict__ loss_acc)
{
  __shared__ float tile[64][65];
  __shared__ float zq[64][65];
  __shared__ float sinv[64];
  __shared__ int sidx[64];
  __shared__ float swsum[4];
  const int t = threadIdx.x;
  const int ct = blockIdx.x & 3;
  const int bh = blockIdx.x >> 2;
  const int c0 = ct * 64;
  const int cl = t >> 2, q = t & 3;
  const float4* zr = (const float4*)(z + ((size_t)(bh >> 6) * 256 + c0 + cl) * 4096
                                       + (size_t)(bh & 63) * 64);
  #pragma unroll
  for (int i = 0; i < 4; i++){
    float4 v = zr[q + 4*i];
    int w = (q + 4*i) * 4;
    tile[cl][w] = v.x; tile[cl][w+1] = v.y; tile[cl][w+2] = v.z; tile[cl][w+3] = v.w;
  }
  if (t < 64) sidx[t] = idx_i[bh*64 + t];
  __syncthreads();
  if (t < 64){
    float ss = 0.f;
    #pragma unroll
    for (int w = 0; w < 64; w++){ float x = tile[t][w]; ss = fmaf(x, x, ss); }
    sinv[t] = 1.0f / fmaxf(sqrtf(ss), 1e-12f);
  }
  __syncthreads();
  {
    const int wvv = t >> 6, l = t & 63;
    #pragma unroll
    for (int i = 0; i < 16; i++){
      int w = wvv * 16 + i;
      zq[l][w] = emb[(size_t)sidx[w] * 256 + c0 + l];
    }
  }
  __syncthreads();
  float lsum = 0.f;
  const int rr = t >> 4, w4 = (t & 15) * 4;
  #pragma unroll
  for (int rd = 0; rd < 4; rd++){
    int r = rr + 16 * rd;
    float inv = sinv[r];
    float q0 = zq[r][w4+0], q1 = zq[r][w4+1], q2 = zq[r][w4+2], q3 = zq[r][w4+3];
    float d0 = q0 - tile[r][w4+0] * inv;
    float d1 = q1 - tile[r][w4+1] * inv;
    float d2 = q2 - tile[r][w4+2] * inv;
    float d3 = q3 - tile[r][w4+3] * inv;
    lsum = fmaf(d0, d0, lsum); lsum = fmaf(d1, d1, lsum);
    lsum = fmaf(d2, d2, lsum); lsum = fmaf(d3, d3, lsum);
    *(float4*)(out + ((size_t)(bh >> 6) * 256 + c0 + r) * 4096
                   + (size_t)(bh & 63) * 64 + w4) = make_float4(q0, q1, q2, q3);
  }
  #pragma unroll
  for (int m = 32; m > 0; m >>= 1) lsum += __shfl_down(lsum, m, 64);
  if ((t & 63) == 0) swsum[t >> 6] = lsum;
  __syncthreads();
  if (t == 0) atomicAdd(loss_acc, swsum[0] + swsum[1] + swsum[2] + swsum[3]);
}

// ---------------- K4: finalize loss = (1 + BETA) * mean
__global__ void kern_final(const float* __restrict__ loss_acc, float* __restrict__ out_loss){
  if (threadIdx.x == 0 && blockIdx.x == 0)
    out_loss[0] = 1.25f * loss_acc[0] * (1.0f / 16777216.0f);
}

extern "C" void kernel_launch(void* const* d_in, const int* in_sizes, int n_in,
                              void* d_out, int out_size, void* d_ws, size_t ws_size,
                              hipStream_t stream)
{
  const float* z   = (const float*)d_in[0];
  const float* emb = (const float*)d_in[1];
  char* ws = (char*)d_ws;
  // workspace layout (~67 MB)
  unsigned int* flag_count = (unsigned int*)(ws + 0);
  float* loss_acc          = (float*)(ws + 8);
  float* wnn               = (float*)(ws + 1024);
  float* wnn4              = (float*)(ws + 8192);
  float* wn                = (float*)(ws + 16384);
  uint4* wnh4              = (uint4*)(ws + 1064960);
  int* idx_i               = (int*)(ws + 1589248);
  int* flag_list           = (int*)(ws + 1851392);
  uint2* pairs             = (uint2*)(ws + 2113536);
  uint4* zfh4              = (uint4*)(ws + 3162112);
  uint4* zfl4              = (uint4*)(ws + 36716544);
  float* out_zq   = (float*)d_out;
  float* out_idx  = (float*)d_out + 16777216;
  float* out_loss = (float*)d_out + 16842752;

  hipMemsetAsync(ws, 0, 16, stream);  // flag_count + loss accumulator
  kern_prep<<<KK, 64, 0, stream>>>(emb, wn, wnh4, wnn, wnn4);
  kern_znorm<<<4096, 256, 0, stream>>>(z, zfh4, zfl4);
  kern_gemm<<<512, 256, 0, stream>>>(zfh4, wnh4, wnn4, pairs);
  kern_merge<<<256, 256, 0, stream>>>(pairs, idx_i, out_idx, flag_list, flag_count);
  kern_rescue<<<512, 256, 0, stream>>>(zfh4, zfl4, wn, wnn, flag_list, flag_count,
                                       idx_i, out_idx);
  kern_gather<<<4096, 256, 0, stream>>>(z, emb, idx_i, out_zq, loss_acc);
  kern_final<<<1, 64, 0, stream>>>(loss_acc, out_loss);
}

// Round 5
// 307.864 us; speedup vs baseline: 2.4870x; 1.2219x over previous
//
#include <hip/hip_runtime.h>

// Problem constants (z: [16,256,64,64] f32, embedding: [1024,256] f32)
#define NN 65536   // B*H*W rows
#define KK 1024
// flag if fixed-point top-2 gap < 2098 (= 4e-3 * 2^19): ~10 sigma of 1-pass bf16 noise
#define TFLAG_FIX 2098u

typedef __bf16 bf16x8 __attribute__((ext_vector_type(8)));
typedef float f32x16 __attribute__((ext_vector_type(16)));

__device__ __forceinline__ unsigned short f2bf(float x){
  unsigned u = __float_as_uint(x);
  u += 0x7FFFu + ((u >> 16) & 1u);
  return (unsigned short)(u >> 16);
}
__device__ __forceinline__ float bf2f(unsigned short h){
  return __uint_as_float(((unsigned)h) << 16);
}
__device__ __forceinline__ void dma16(const uint4* g, uint4* l){
  __builtin_amdgcn_global_load_lds(
      (const __attribute__((address_space(1))) void*)g,
      (__attribute__((address_space(3))) void*)l, 16, 0, 0);
}
__device__ __forceinline__ unsigned long long shfl_xor_u64(unsigned long long v, int m){
  unsigned lo = (unsigned)__shfl_xor((int)(unsigned)v, m, 64);
  unsigned hi = (unsigned)__shfl_xor((int)(unsigned)(v >> 32), m, 64);
  return ((unsigned long long)hi << 32) | lo;
}
union U4S8 { uint4 v; unsigned short u[8]; };

// Fragment-major layout for bf16 matrices [rows][256 c]:
// uint4 (8 c-elems) for (row n, chunk q=c>>3) at index (n>>5)*1024 + q*32 + (n&31).

// ---------------- K0: normalize codebook, write wn(f32), wnh frag-major, wnn, wnn4
__global__ __launch_bounds__(64) void kern_prep(const float* __restrict__ emb,
    float* __restrict__ wn, uint4* __restrict__ wnh4,
    float* __restrict__ wnn, float* __restrict__ wnn4)
{
  const int k = blockIdx.x, t = threadIdx.x;
  float4 v = ((const float4*)emb)[k*64 + t];
  float ss = fmaf(v.x, v.x, fmaf(v.y, v.y, fmaf(v.z, v.z, v.w * v.w)));
  #pragma unroll
  for (int m = 32; m > 0; m >>= 1) ss += __shfl_xor(ss, m, 64);
  float d = fmaxf(sqrtf(ss), 1e-12f);
  float w0 = v.x / d, w1 = v.y / d, w2 = v.z / d, w3 = v.w / d;
  ((float4*)wn)[k*64 + t] = make_float4(w0, w1, w2, w3);
  unsigned short* base = (unsigned short*)wnh4;
  size_t o = ((size_t)(k >> 5) * 1024 + (size_t)(t >> 1) * 32 + (k & 31)) * 8 + (t & 1) * 4;
  base[o+0] = f2bf(w0); base[o+1] = f2bf(w1); base[o+2] = f2bf(w2); base[o+3] = f2bf(w3);
  float s2 = fmaf(w0, w0, fmaf(w1, w1, fmaf(w2, w2, w3 * w3)));
  #pragma unroll
  for (int m = 32; m > 0; m >>= 1) s2 += __shfl_xor(s2, m, 64);
  if (t == 0){ wnn[k] = s2; wnn4[k] = 4.0f - s2; }
}

// ---------------- K1: L2-normalize z along W, transpose to [N,C], split bf16 hi/lo,
// store BOTH in fragment-major layout. grid: (b*64+h)*4 + c-tile; block 256.
__global__ __launch_bounds__(256) void kern_znorm(const float* __restrict__ z,
    uint4* __restrict__ zfh4, uint4* __restrict__ zfl4)
{
  __shared__ float tile[64][65];  // [c_local][w]
  __shared__ float sinv[64];
  const int t = threadIdx.x;
  const int ct = blockIdx.x & 3;
  const int bh = blockIdx.x >> 2;     // b*64 + h
  const int c0 = ct * 64, q0 = ct * 8;
  const int cl = t >> 2, q = t & 3;
  const float4* zr = (const float4*)(z + ((size_t)(bh >> 6) * 256 + c0 + cl) * 4096
                                       + (size_t)(bh & 63) * 64);
  #pragma unroll
  for (int i = 0; i < 4; i++){
    float4 v = zr[q + 4*i];
    int w = (q + 4*i) * 4;
    tile[cl][w] = v.x; tile[cl][w+1] = v.y; tile[cl][w+2] = v.z; tile[cl][w+3] = v.w;
  }
  __syncthreads();
  if (t < 64){
    float ss = 0.f;
    #pragma unroll
    for (int w = 0; w < 64; w++){ float x = tile[t][w]; ss = fmaf(x, x, ss); }
    sinv[t] = 1.0f / fmaxf(sqrtf(ss), 1e-12f);
  }
  __syncthreads();
  #pragma unroll
  for (int j = 0; j < 2; j++){
    int p = t + 256 * j;
    int tI = p >> 8, rem = p & 255;
    int qq = rem >> 5, colI = rem & 31;
    int w = tI * 32 + colI;
    U4S8 hh, ll;
    #pragma unroll
    for (int e = 0; e < 8; e++){
      int c = qq * 8 + e;
      float v = tile[c][w] * sinv[c];
      hh.u[e] = f2bf(v);
      ll.u[e] = f2bf(v - bf2f(hh.u[e]));
    }
    size_t o = (size_t)(bh * 2 + tI) * 1024 + (size_t)(q0 + qq) * 32 + colI;
    zfh4[o] = hh.v;
    zfl4[o] = ll.v;
  }
}

// ---------------- K2: 1-pass bf16 MFMA GEMM, 64 rows x 32 codes per wave,
// code-split-2, DMA-staged double-buffered B, fixed-point packed-key top-2 per row.
__global__ __launch_bounds__(256, 2) void kern_gemm(
    const uint4* __restrict__ zA, const uint4* __restrict__ wB,
    const float* __restrict__ wnn4, uint2* __restrict__ pairs)
{
  __shared__ uint4 sB[2][1024];
  const int t = threadIdx.x;
  const int wv = t >> 6;
  const int lane = t & 63;
  const int col = lane & 31;
  const int half = lane >> 5;
  const int hb = blockIdx.x & 1;
  const int cb = hb * 512;
  const int rowBase = (blockIdx.x >> 1) * 256 + wv * 64;
  const int T0 = rowBase >> 5;

  bf16x8 a0[16], a1[16];
  {
    const uint4* r0 = zA + (size_t)T0 * 1024;
    const uint4* r1 = zA + (size_t)(T0 + 1) * 1024;
    const uint4* g0 = wB + (size_t)(cb >> 5) * 1024;
    dma16(g0 + (wv*4+0)*64 + lane, &sB[0][(wv*4+0)*64 + lane]);
    dma16(g0 + (wv*4+1)*64 + lane, &sB[0][(wv*4+1)*64 + lane]);
    dma16(g0 + (wv*4+2)*64 + lane, &sB[0][(wv*4+2)*64 + lane]);
    dma16(g0 + (wv*4+3)*64 + lane, &sB[0][(wv*4+3)*64 + lane]);
    #pragma unroll
    for (int s = 0; s < 16; s++){
      a0[s] = __builtin_bit_cast(bf16x8, r0[(2*s + half)*32 + col]);
      a1[s] = __builtin_bit_cast(bf16x8, r1[(2*s + half)*32 + col]);
    }
  }
  unsigned b1k[2][16], b2k[2][16];
  #pragma unroll
  for (int r = 0; r < 16; r++){
    b1k[0][r] = 0u; b1k[1][r] = 0u; b2k[0][r] = 0u; b2k[1][r] = 0u;
  }
  const int kinvBase = 1023 - cb - col;
  __syncthreads();

  for (int kt = 0; kt < 16; kt++){
    if (kt < 15){
      const uint4* gn = wB + (size_t)((cb >> 5) + kt + 1) * 1024;
      uint4* ld = &sB[(kt + 1) & 1][0];
      dma16(gn + (wv*4+0)*64 + lane, ld + (wv*4+0)*64 + lane);
      dma16(gn + (wv*4+1)*64 + lane, ld + (wv*4+1)*64 + lane);
      dma16(gn + (wv*4+2)*64 + lane, ld + (wv*4+2)*64 + lane);
      dma16(gn + (wv*4+3)*64 + lane, ld + (wv*4+3)*64 + lane);
    }
    const float c4k = wnn4[cb + kt*32 + col];
    const uint4* bp = &sB[kt & 1][half * 32 + col];
    f32x16 acc0, acc1;
    #pragma unroll
    for (int i = 0; i < 16; i++){ acc0[i] = 0.0f; acc1[i] = 0.0f; }
    #pragma unroll
    for (int s = 0; s < 16; s++){
      bf16x8 bs = __builtin_bit_cast(bf16x8, bp[s * 64]);
      acc0 = __builtin_amdgcn_mfma_f32_32x32x16_bf16(a0[s], bs, acc0, 0, 0, 0);
      acc1 = __builtin_amdgcn_mfma_f32_32x32x16_bf16(a1[s], bs, acc1, 0, 0, 0);
    }
    const unsigned kinv = (unsigned)(kinvBase - kt * 32);
    #pragma unroll
    for (int r = 0; r < 16; r++){
      // s'' = 4 - ||w||^2 + 2*dot in [1,5]; fixed-point *2^19 (trunc, monotone)
      float s0 = fmaf(2.0f, acc0[r], c4k);
      unsigned u0 = ((unsigned)(s0 * 524288.0f) << 10) | kinv;
      b2k[0][r] = max(b2k[0][r], min(b1k[0][r], u0));
      b1k[0][r] = max(b1k[0][r], u0);
      float s1 = fmaf(2.0f, acc1[r], c4k);
      unsigned u1 = ((unsigned)(s1 * 524288.0f) << 10) | kinv;
      b2k[1][r] = max(b2k[1][r], min(b1k[1][r], u1));
      b1k[1][r] = max(b1k[1][r], u1);
    }
    __syncthreads();
  }
  #pragma unroll
  for (int m = 1; m < 32; m <<= 1){
    #pragma unroll
    for (int ti = 0; ti < 2; ti++){
      #pragma unroll
      for (int r = 0; r < 16; r++){
        unsigned o1 = (unsigned)__shfl_xor((int)b1k[ti][r], m, 64);
        unsigned o2 = (unsigned)__shfl_xor((int)b2k[ti][r], m, 64);
        b2k[ti][r] = max(max(b2k[ti][r], o2), min(b1k[ti][r], o1));
        b1k[ti][r] = max(b1k[ti][r], o1);
      }
    }
  }
  if (col == 0){
    #pragma unroll
    for (int ti = 0; ti < 2; ti++){
      #pragma unroll
      for (int r = 0; r < 16; r++){
        int rowD = (r & 3) + 8 * (r >> 2) + 4 * half;  // verified C/D map [m74/m101]
        int n = rowBase + ti * 32 + rowD;
        pairs[(size_t)n * 2 + hb] = make_uint2(b1k[ti][r], b2k[ti][r]);
      }
    }
  }
}

// ---------------- K2m: merge two code-half top-2s, emit idx + flags (integer gap)
__global__ __launch_bounds__(256) void kern_merge(
    const uint2* __restrict__ pairs, int* __restrict__ idx_i, float* __restrict__ idx_f,
    int* __restrict__ flag_list, unsigned int* __restrict__ flag_count)
{
  const int n = blockIdx.x * 256 + threadIdx.x;
  uint2 p0 = pairs[(size_t)n * 2];
  uint2 p1 = pairs[(size_t)n * 2 + 1];
  unsigned B1 = max(p0.x, p1.x);
  unsigned B2 = max(max(p0.y, p1.y), min(p0.x, p1.x));
  int idx = 1023 - (int)(B1 & 1023u);
  idx_i[n] = idx;
  idx_f[n] = (float)idx;
  bool f = ((B1 >> 10) - (B2 >> 10)) < TFLAG_FIX;
  unsigned long long m = __ballot(f);
  if (m){
    int lane = threadIdx.x & 63;
    int leader = __ffsll((unsigned long long)m) - 1;
    unsigned base = 0;
    if (lane == leader) base = atomicAdd(flag_count, (unsigned)__popcll(m));
    base = (unsigned)__shfl((int)base, leader, 64);
    if (f){
      int off = __popcll(m & ((1ull << lane) - 1ull));
      flag_list[base + off] = n;
    }
  }
}

// ---------------- K2b: exact-fp32 rescore of flagged rows. Per-(row,k) chain is
// BIT-IDENTICAL to the R1/R3-validated rescue: serial fp32 fmaf over c=0..255
// (zf = hi+lo), s = fmaf(-2, dot, wnn[k]), argmin with lowest-index tie-break
// (realized exactly via 64-bit (orderable-float, k) key min-reduce).
// Fully static indexing everywhere -> acc stays in VGPRs (R4 spilled via the
// runtime-bound r-loop; VGPR=60 + 33 MB scratch writes was the 146 us).
__global__ __launch_bounds__(256) void kern_rescue(
    const uint4* __restrict__ zfh4, const uint4* __restrict__ zfl4,
    const float* __restrict__ wn, const float* __restrict__ wnn,
    const int* __restrict__ flag_list, const unsigned int* __restrict__ flag_count,
    int* __restrict__ idx_i, float* __restrict__ idx_f)
{
  __shared__ float sz[16][256];
  __shared__ unsigned long long sred[4][16];
  __shared__ int srow[16];
  const int t = threadIdx.x;
  const int lane = t & 63, wvi = t >> 6;
  const int cnt = (int)*flag_count;
  const int k0 = t * 4;
  const float wq0 = wnn[k0+0], wq1 = wnn[k0+1], wq2 = wnn[k0+2], wq3 = wnn[k0+3];

  for (int base = blockIdx.x * 16; base < cnt; base += gridDim.x * 16){
    const int nr = min(16, cnt - base);
    __syncthreads();
    if (t < 16) srow[t] = flag_list[base + min(t, nr - 1)];  // pad: duplicate last row
    __syncthreads();
    #pragma unroll
    for (int j = 0; j < 2; j++){
      int p = t + j * 256;
      int r = p >> 5, q = p & 31;
      int n = srow[r];
      size_t o = (size_t)(n >> 5) * 1024 + (size_t)q * 32 + (n & 31);
      U4S8 h, l; h.v = zfh4[o]; l.v = zfl4[o];
      #pragma unroll
      for (int e = 0; e < 8; e++) sz[r][q*8+e] = bf2f(h.u[e]) + bf2f(l.u[e]);
    }
    __syncthreads();

    float acc[4][16];
    #pragma unroll
    for (int j = 0; j < 4; j++)
      #pragma unroll
      for (int r = 0; r < 16; r++) acc[j][r] = 0.0f;
    const float4* w0 = (const float4*)(wn + (size_t)(k0+0)*256);
    const float4* w1 = (const float4*)(wn + (size_t)(k0+1)*256);
    const float4* w2 = (const float4*)(wn + (size_t)(k0+2)*256);
    const float4* w3 = (const float4*)(wn + (size_t)(k0+3)*256);
    for (int c4 = 0; c4 < 64; c4++){
      float4 wa = w0[c4], wb = w1[c4], wc = w2[c4], wd = w3[c4];
      #pragma unroll
      for (int r = 0; r < 16; r++){
        float4 s = ((const float4*)sz[r])[c4];   // broadcast LDS read
        acc[0][r] = fmaf(s.x, wa.x, acc[0][r]);
        acc[0][r] = fmaf(s.y, wa.y, acc[0][r]);
        acc[0][r] = fmaf(s.z, wa.z, acc[0][r]);
        acc[0][r] = fmaf(s.w, wa.w, acc[0][r]);
        acc[1][r] = fmaf(s.x, wb.x, acc[1][r]);
        acc[1][r] = fmaf(s.y, wb.y, acc[1][r]);
        acc[1][r] = fmaf(s.z, wb.z, acc[1][r]);
        acc[1][r] = fmaf(s.w, wb.w, acc[1][r]);
        acc[2][r] = fmaf(s.x, wc.x, acc[2][r]);
        acc[2][r] = fmaf(s.y, wc.y, acc[2][r]);
        acc[2][r] = fmaf(s.z, wc.z, acc[2][r]);
        acc[2][r] = fmaf(s.w, wc.w, acc[2][r]);
        acc[3][r] = fmaf(s.x, wd.x, acc[3][r]);
        acc[3][r] = fmaf(s.y, wd.y, acc[3][r]);
        acc[3][r] = fmaf(s.z, wd.z, acc[3][r]);
        acc[3][r] = fmaf(s.w, wd.w, acc[3][r]);
      }
    }
    #pragma unroll
    for (int r = 0; r < 16; r++){
      float s0 = fmaf(-2.0f, acc[0][r], wq0);
      float s1 = fmaf(-2.0f, acc[1][r], wq1);
      float s2 = fmaf(-2.0f, acc[2][r], wq2);
      float s3 = fmaf(-2.0f, acc[3][r], wq3);
      float bv = s0; int bi = k0;
      if (s1 < bv){ bv = s1; bi = k0 + 1; }
      if (s2 < bv){ bv = s2; bi = k0 + 2; }
      if (s3 < bv){ bv = s3; bi = k0 + 3; }
      unsigned u = __float_as_uint(bv);
      u = (u & 0x80000000u) ? ~u : (u | 0x80000000u);   // orderable float
      unsigned long long key = ((unsigned long long)u << 10) | (unsigned)bi;
      #pragma unroll
      for (int m = 1; m < 64; m <<= 1){
        unsigned long long o = shfl_xor_u64(key, m);
        if (o < key) key = o;
      }
      if (lane == 0) sred[wvi][r] = key;
    }
    __syncthreads();
    if (t < nr){
      unsigned long long ka = sred[0][t] < sred[1][t] ? sred[0][t] : sred[1][t];
      unsigned long long kb = sred[2][t] < sred[3][t] ? sred[2][t] : sred[3][t];
      unsigned long long kf = ka < kb ? ka : kb;
      int fi = (int)(kf & 1023ull);
      idx_i[srow[t]] = fi;
      idx_f[srow[t]] = (float)fi;
    }
  }
}

// ---------------- K3: gather z_q = embedding[idx] back to [B,C,H,W] + loss sum
__global__ __launch_bounds__(256) void kern_gather(
    const float* __restrict__ z, const float* __restrict__ emb,
    const int* __restrict__ idx_i, float* __restrict__ out,
    float* __restrict__ loss_acc)
{
  __shared__ float tile[64][65];
  __shared__ float zq[64][65];
  __shared__ float sinv[64];
  __shared__ int sidx[64];
  __shared__ float swsum[4];
  const int t = threadIdx.x;
  const int ct = blockIdx.x & 3;
  const int bh = blockIdx.x >> 2;
  const int c0 = ct * 64;
  const int cl = t >> 2, q = t & 3;
  const float4* zr = (const float4*)(z + ((size_t)(bh >> 6) * 256 + c0 + cl) * 4096
                                       + (size_t)(bh & 63) * 64);
  #pragma unroll
  for (int i = 0; i < 4; i++){
    float4 v = zr[q + 4*i];
    int w = (q + 4*i) * 4;
    tile[cl][w] = v.x; tile[cl][w+1] = v.y; tile[cl][w+2] = v.z; tile[cl][w+3] = v.w;
  }
  if (t < 64) sidx[t] = idx_i[bh*64 + t];
  __syncthreads();
  if (t < 64){
    float ss = 0.f;
    #pragma unroll
    for (int w = 0; w < 64; w++){ float x = tile[t][w]; ss = fmaf(x, x, ss); }
    sinv[t] = 1.0f / fmaxf(sqrtf(ss), 1e-12f);
  }
  __syncthreads();
  {
    const int wvv = t >> 6, l = t & 63;
    #pragma unroll
    for (int i = 0; i < 16; i++){
      int w = wvv * 16 + i;
      zq[l][w] = emb[(size_t)sidx[w] * 256 + c0 + l];
    }
  }
  __syncthreads();
  float lsum = 0.f;
  const int rr = t >> 4, w4 = (t & 15) * 4;
  #pragma unroll
  for (int rd = 0; rd < 4; rd++){
    int r = rr + 16 * rd;
    float inv = sinv[r];
    float q0 = zq[r][w4+0], q1 = zq[r][w4+1], q2 = zq[r][w4+2], q3 = zq[r][w4+3];
    float d0 = q0 - tile[r][w4+0] * inv;
    float d1 = q1 - tile[r][w4+1] * inv;
    float d2 = q2 - tile[r][w4+2] * inv;
    float d3 = q3 - tile[r][w4+3] * inv;
    lsum = fmaf(d0, d0, lsum); lsum = fmaf(d1, d1, lsum);
    lsum = fmaf(d2, d2, lsum); lsum = fmaf(d3, d3, lsum);
    *(float4*)(out + ((size_t)(bh >> 6) * 256 + c0 + r) * 4096
                   + (size_t)(bh & 63) * 64 + w4) = make_float4(q0, q1, q2, q3);
  }
  #pragma unroll
  for (int m = 32; m > 0; m >>= 1) lsum += __shfl_down(lsum, m, 64);
  if ((t & 63) == 0) swsum[t >> 6] = lsum;
  __syncthreads();
  if (t == 0) atomicAdd(loss_acc, swsum[0] + swsum[1] + swsum[2] + swsum[3]);
}

// ---------------- K4: finalize loss = (1 + BETA) * mean
__global__ void kern_final(const float* __restrict__ loss_acc, float* __restrict__ out_loss){
  if (threadIdx.x == 0 && blockIdx.x == 0)
    out_loss[0] = 1.25f * loss_acc[0] * (1.0f / 16777216.0f);
}

extern "C" void kernel_launch(void* const* d_in, const int* in_sizes, int n_in,
                              void* d_out, int out_size, void* d_ws, size_t ws_size,
                              hipStream_t stream)
{
  const float* z   = (const float*)d_in[0];
  const float* emb = (const float*)d_in[1];
  char* ws = (char*)d_ws;
  unsigned int* flag_count = (unsigned int*)(ws + 0);
  float* loss_acc          = (float*)(ws + 8);
  float* wnn               = (float*)(ws + 1024);
  float* wnn4              = (float*)(ws + 8192);
  float* wn                = (float*)(ws + 16384);
  uint4* wnh4              = (uint4*)(ws + 1064960);
  int* idx_i               = (int*)(ws + 1589248);
  int* flag_list           = (int*)(ws + 1851392);
  uint2* pairs             = (uint2*)(ws + 2113536);
  uint4* zfh4              = (uint4*)(ws + 3162112);
  uint4* zfl4              = (uint4*)(ws + 36716544);
  float* out_zq   = (float*)d_out;
  float* out_idx  = (float*)d_out + 16777216;
  float* out_loss = (float*)d_out + 16842752;

  hipMemsetAsync(ws, 0, 16, stream);  // flag_count + loss accumulator
  kern_prep<<<KK, 64, 0, stream>>>(emb, wn, wnh4, wnn, wnn4);
  kern_znorm<<<4096, 256, 0, stream>>>(z, zfh4, zfl4);
  kern_gemm<<<512, 256, 0, stream>>>(zfh4, wnh4, wnn4, pairs);
  kern_merge<<<256, 256, 0, stream>>>(pairs, idx_i, out_idx, flag_list, flag_count);
  kern_rescue<<<512, 256, 0, stream>>>(zfh4, zfl4, wn, wnn, flag_list, flag_count,
                                       idx_i, out_idx);
  kern_gather<<<4096, 256, 0, stream>>>(z, emb, idx_i, out_zq, loss_acc);
  kern_final<<<1, 64, 0, stream>>>(loss_acc, out_loss);
}